// Round 8
// baseline (1804.960 us; speedup 1.0000x reference)
//
#include <hip/hip_runtime.h>

#define TT 4096
#define BB 128
#define L2E 1.4426950408889634f

typedef unsigned uv2 __attribute__((ext_vector_type(2)));
typedef float v2f __attribute__((ext_vector_type(2)));

__device__ __forceinline__ float fexp2(float a) {
  return __builtin_amdgcn_exp2f(a);  // v_exp_f32: 2^a
}

__device__ __forceinline__ float bpermf(int idx_bytes, float v) {
  return __int_as_float(__builtin_amdgcn_ds_bpermute(idx_bytes, __float_as_int(v)));
}

// Sum of p with partner half (lane ^ 32), replicated in both halves. Pure VALU.
__device__ __forceinline__ float xhalf_sum(float p) {
#if __has_builtin(__builtin_amdgcn_permlane32_swap)
  uv2 r = __builtin_amdgcn_permlane32_swap(__float_as_uint(p), __float_as_uint(p),
                                           false, false);
  return __uint_as_float(r[0]) + __uint_as_float(r[1]);
#else
  return p + bpermf((threadIdx.x ^ 32) << 2, p);
#endif
}

// gx[b,t,g]: g<64 -> 0.5*(x.w_ih[g] + b_ih[g] + b_hh[g])   (r,z; halved for cross-half sum)
//            g>=64 -> x.w_ih[g] + b_ih[g]                  (n x-side, full, per-lane)
__global__ __launch_bounds__(256) void gx_pre(
    const float* __restrict__ x, const float* __restrict__ w_ih,
    const float* __restrict__ b_ih, const float* __restrict__ b_hh,
    float* __restrict__ gx) {
  const size_t idx = (size_t)blockIdx.x * 256 + threadIdx.x;  // (b*T+t)*96+g
  const int g = (int)(idx % 96);
  const size_t bt = idx / 96;
  const float* xp = x + bt * 6;
  float acc = (g < 64) ? (b_ih[g] + b_hh[g]) : b_ih[g];
#pragma unroll
  for (int i = 0; i < 6; ++i) acc = fmaf(w_ih[g * 6 + i], xp[i], acc);
  gx[idx] = (g < 64) ? 0.5f * acc : acc;
}

// One wave per batch element. Lane l: j = l&31 owns gate rows j/32+j/64+j;
// half = l>>5 picks the 16-wide K-slice. Invariant: h register holds h[l&31].
// Per-step h store goes through a 4-slot rotating temp (forced v_mov) so the
// store's source-register reuse wait (vmcnt) has 4 steps of slack instead of 1.
__global__ __launch_bounds__(64, 1)
void gru_seq(const int* __restrict__ lengths, const float* __restrict__ w_hh,
             const float* __restrict__ b_hh, const float* __restrict__ gx,
             float* __restrict__ hbuf) {
  const int b = blockIdx.x;
  const int l = threadIdx.x;
  const int j = l & 31;
  const int half = l >> 5;
  const int ko = half << 4;
  const int len = lengths[b];

  // raw 16-wide K-slices as float2 pairs (v_pk_fma_f32 operands)
  v2f wr2[8], wz2[8], wn2[8];
  {
    const v2f* pr = (const v2f*)(w_hh + j * 32 + ko);
    const v2f* pz = (const v2f*)(w_hh + (32 + j) * 32 + ko);
    const v2f* pn = (const v2f*)(w_hh + (64 + j) * 32 + ko);
#pragma unroll
    for (int k = 0; k < 8; ++k) wr2[k] = pr[k];
#pragma unroll
    for (int k = 0; k < 8; ++k) wz2[k] = pz[k];
#pragma unroll
    for (int k = 0; k < 8; ++k) wn2[k] = pn[k];
  }
  const float bhn = 0.5f * b_hh[64 + j];  // halved: cross-half sum doubles it

  const float* gxb = gx + (size_t)b * TT * 96;
  float* hrow = hbuf + (size_t)b * TT * 32;
  const int bko = half << 6;  // bpermute byte-index base (ko*4)

  float h = 0.0f;
  int t = 0;

  // 4-deep gx prefetch slots + 4 rotating store temps (named; static indexing)
  float g0r, g0z, g0n, g1r, g1z, g1n, g2r, g2z, g2n, g3r, g3z, g3n;
  float hs0 = 0.f, hs1 = 0.f, hs2 = 0.f, hs3 = 0.f;
  {
    const int t1 = (1 < len) ? 1 : len - 1, t2 = (2 < len) ? 2 : len - 1,
              t3 = (3 < len) ? 3 : len - 1;
    const float *p0 = gxb, *p1 = gxb + (size_t)t1 * 96,
                *p2 = gxb + (size_t)t2 * 96, *p3 = gxb + (size_t)t3 * 96;
    g0r = p0[j]; g0z = p0[32 + j]; g0n = p0[64 + j];
    g1r = p1[j]; g1z = p1[32 + j]; g1n = p1[64 + j];
    g2r = p2[j]; g2z = p2[32 + j]; g2n = p2[64 + j];
    g3r = p3[j]; g3z = p3[32 + j]; g3n = p3[64 + j];
  }

  auto step = [&](float& GR, float& GZ, float& GN, float& HS) {
    // broadcast this half's 16 h values into 8 register pairs
    v2f hbv[8];
#pragma unroll
    for (int k = 0; k < 8; ++k) {
      hbv[k][0] = bpermf(bko + (k << 3), h);
      hbv[k][1] = bpermf(bko + (k << 3) + 4, h);
    }

    const float xr_ = GR, xz_ = GZ, xn_ = GN;
    // refill this slot for t+4 (completes within the next 3 iterations)
    {
      const int tp = (t + 4 < len) ? (t + 4) : (len - 1);
      const float* gp = gxb + (size_t)tp * 96;
      GR = gp[j]; GZ = gp[32 + j]; GN = gp[64 + j];
    }

    // 48 MACs as 24 v_pk_fma_f32, 8-deep chains
    v2f ar = {xr_, 0.f}, az = {xz_, 0.f}, an = {bhn, 0.f};
#pragma unroll
    for (int k = 0; k < 8; ++k) {
      ar = __builtin_elementwise_fma(wr2[k], hbv[k], ar);
      az = __builtin_elementwise_fma(wz2[k], hbv[k], az);
      an = __builtin_elementwise_fma(wn2[k], hbv[k], an);
    }
    const float sr = xhalf_sum(ar[0] + ar[1]);
    const float r = __builtin_amdgcn_rcpf(1.0f + fexp2(-L2E * sr));
    const float sz = xhalf_sum(az[0] + az[1]);
    const float z = __builtin_amdgcn_rcpf(1.0f + fexp2(-L2E * sz));
    const float hn = xhalf_sum(an[0] + an[1]);
    const float ap = fmaf(r, hn, xn_);
    const float qq = __builtin_amdgcn_rcpf(1.0f + fexp2(-2.0f * L2E * ap));
    const float nn = fmaf(2.0f, qq, -1.0f);
    h = fmaf(z, h - nn, nn);

    // forced copy: the store reads HS, not h, so overwriting h next step
    // needs no vmcnt wait; HS is reused 4 steps later.
    asm volatile("v_mov_b32 %0, %1" : "=v"(HS) : "v"(h));
    hrow[t * 32 + j] = HS;
    ++t;
  };

  while (t + 4 <= len) {
    step(g0r, g0z, g0n, hs0);
    step(g1r, g1z, g1n, hs1);
    step(g2r, g2z, g2n, hs2);
    step(g3r, g3z, g3n, hs3);
  }
  if (t < len) step(g0r, g0z, g0n, hs0);
  if (t < len) step(g1r, g1z, g1n, hs1);
  if (t < len) step(g2r, g2z, g2n, hs2);
}

// out[b,t,:] = (t < len[b]) ? h[b,t,:] @ fc_w^T + fc_b : fc_b
__global__ __launch_bounds__(256) void fc_apply(
    const float* __restrict__ hbuf, const int* __restrict__ lengths,
    const float* __restrict__ fc_w, const float* __restrict__ fc_b,
    float* __restrict__ out) {
  const int idx = blockIdx.x * 256 + threadIdx.x;  // flattened (b,t)
  const int b = idx >> 12;
  const int t = idx & (TT - 1);
  const float fb0 = fc_b[0], fb1 = fc_b[1];
  float* op = out + (size_t)idx * 2;
  if (t >= lengths[b]) {
    op[0] = fb0;
    op[1] = fb1;
    return;
  }
  const float4* hp = (const float4*)(hbuf + (size_t)idx * 32);
  const float4* w0 = (const float4*)(fc_w);
  const float4* w1 = (const float4*)(fc_w + 32);
  float o0 = 0.f, o1 = 0.f;
#pragma unroll
  for (int q = 0; q < 8; ++q) {
    const float4 hv = hp[q], a = w0[q], c = w1[q];
    o0 += hv.x * a.x + hv.y * a.y + hv.z * a.z + hv.w * a.w;
    o1 += hv.x * c.x + hv.y * c.y + hv.z * c.z + hv.w * c.w;
  }
  op[0] = o0 + fb0;
  op[1] = o1 + fb1;
}

// Fallback (ws too small): self-contained single kernel.
__global__ __launch_bounds__(64, 1) void gru_fallback(
    const float* __restrict__ x, const int* __restrict__ lengths,
    const float* __restrict__ w_ih, const float* __restrict__ w_hh,
    const float* __restrict__ b_ih, const float* __restrict__ b_hh,
    const float* __restrict__ fc_w, const float* __restrict__ fc_b,
    float* __restrict__ out) {
  const int b = blockIdx.x;
  const int l = threadIdx.x;
  const int j = l & 31;
  const int half = l >> 5;
  const int ko = half << 4;
  const int len = lengths[b];

  float wr[16], wz[16], wn[16];
#pragma unroll
  for (int k = 0; k < 16; ++k) wr[k] = w_hh[j * 32 + ko + k] * L2E;
#pragma unroll
  for (int k = 0; k < 16; ++k) wz[k] = w_hh[(32 + j) * 32 + ko + k] * L2E;
#pragma unroll
  for (int k = 0; k < 16; ++k) wn[k] = w_hh[(64 + j) * 32 + ko + k] * (2.0f * L2E);
  float wxr[6], wxz[6], wxn[6];
#pragma unroll
  for (int i = 0; i < 6; ++i) wxr[i] = w_ih[j * 6 + i] * (0.5f * L2E);
#pragma unroll
  for (int i = 0; i < 6; ++i) wxz[i] = w_ih[(32 + j) * 6 + i] * (0.5f * L2E);
#pragma unroll
  for (int i = 0; i < 6; ++i) wxn[i] = w_ih[(64 + j) * 6 + i] * (2.0f * L2E);
  const float br = (b_ih[j] + b_hh[j]) * (0.5f * L2E);
  const float bz = (b_ih[32 + j] + b_hh[32 + j]) * (0.5f * L2E);
  const float bxn = b_ih[64 + j] * (2.0f * L2E);
  const float bhn = b_hh[64 + j] * L2E;
  const float fcw = fc_w[half * 32 + j];
  const float fcb = fc_b[half];

  const float* xb = x + (size_t)b * (TT * 6);
  float* ob = out + (size_t)b * (TT * 2);
  const int bko = half << 6;
  float h = 0.0f;

  v2f cx[3], nx[3];
  {
    const v2f* xp = (const v2f*)xb;
    cx[0] = xp[0]; cx[1] = xp[1]; cx[2] = xp[2];
  }
  for (int t = 0; t < len; ++t) {
    const int tn = (t + 1 < len) ? (t + 1) : t;
    const v2f* xp = (const v2f*)(xb + tn * 6);
    nx[0] = xp[0]; nx[1] = xp[1]; nx[2] = xp[2];
    float xr = br, xz = bz, xn = bxn;
#pragma unroll
    for (int i = 0; i < 3; ++i) {
      const float c0 = cx[i][0], c1 = cx[i][1];
      xr = fmaf(wxr[2 * i], c0, xr); xr = fmaf(wxr[2 * i + 1], c1, xr);
      xz = fmaf(wxz[2 * i], c0, xz); xz = fmaf(wxz[2 * i + 1], c1, xz);
      xn = fmaf(wxn[2 * i], c0, xn); xn = fmaf(wxn[2 * i + 1], c1, xn);
    }
    float hbv[16];
#pragma unroll
    for (int k = 0; k < 16; ++k) hbv[k] = bpermf(bko + (k << 2), h);
    float ar0 = xr, ar1 = 0.f, az0 = xz, az1 = 0.f, an0 = bhn, an1 = 0.f;
#pragma unroll
    for (int k = 0; k < 8; ++k) {
      ar0 = fmaf(wr[k], hbv[k], ar0);
      ar1 = fmaf(wr[k + 8], hbv[k + 8], ar1);
      az0 = fmaf(wz[k], hbv[k], az0);
      az1 = fmaf(wz[k + 8], hbv[k + 8], az1);
      an0 = fmaf(wn[k], hbv[k], an0);
      an1 = fmaf(wn[k + 8], hbv[k + 8], an1);
    }
    const float sr = xhalf_sum(ar0 + ar1);
    const float r = __builtin_amdgcn_rcpf(1.0f + fexp2(-sr));
    const float sz = xhalf_sum(az0 + az1);
    const float z = __builtin_amdgcn_rcpf(1.0f + fexp2(-sz));
    const float hn = xhalf_sum(an0 + an1);
    const float ap = fmaf(r, hn, xn);
    const float qq = __builtin_amdgcn_rcpf(1.0f + fexp2(-ap));
    const float nn = fmaf(2.0f, qq, -1.0f);
    h = fmaf(z, h - nn, nn);
    float p = h * fcw;
    p += __shfl_xor(p, 1);
    p += __shfl_xor(p, 2);
    p += __shfl_xor(p, 4);
    p += __shfl_xor(p, 8);
    p += __shfl_xor(p, 16);
    if (j == 0) ob[t * 2 + half] = p + fcb;
#pragma unroll
    for (int i = 0; i < 3; ++i) cx[i] = nx[i];
  }
  const float fb0 = fc_b[0], fb1 = fc_b[1];
  for (int idx = len * 2 + l; idx < TT * 2; idx += 64)
    ob[idx] = (idx & 1) ? fb1 : fb0;
}

extern "C" void kernel_launch(void* const* d_in, const int* in_sizes, int n_in,
                              void* d_out, int out_size, void* d_ws, size_t ws_size,
                              hipStream_t stream) {
  const float* x       = (const float*)d_in[0];
  const int*   lengths = (const int*)d_in[1];
  const float* w_ih    = (const float*)d_in[2];
  const float* w_hh    = (const float*)d_in[3];
  const float* b_ih    = (const float*)d_in[4];
  const float* b_hh    = (const float*)d_in[5];
  const float* fc_w    = (const float*)d_in[6];
  const float* fc_b    = (const float*)d_in[7];
  float* outp = (float*)d_out;

  const size_t hbuf_elems = (size_t)BB * TT * 32;               // 64 MB
  const size_t gx_elems   = (size_t)BB * TT * 96;               // 192 MB
  const size_t need = (hbuf_elems + gx_elems) * sizeof(float);  // 256 MB
  if (ws_size >= need) {
    float* hbuf = (float*)d_ws;
    float* gx = (float*)d_ws + hbuf_elems;
    hipLaunchKernelGGL(gx_pre, dim3((BB * TT * 96) / 256), dim3(256), 0, stream,
                       x, w_ih, b_ih, b_hh, gx);
    hipLaunchKernelGGL(gru_seq, dim3(BB), dim3(64), 0, stream,
                       lengths, w_hh, b_hh, gx, hbuf);
    hipLaunchKernelGGL(fc_apply, dim3((BB * TT) / 256), dim3(256), 0, stream,
                       hbuf, lengths, fc_w, fc_b, outp);
  } else {
    hipLaunchKernelGGL(gru_fallback, dim3(BB), dim3(64), 0, stream,
                       x, lengths, w_ih, w_hh, b_ih, b_hh, fc_w, fc_b, outp);
  }
}

// Round 9
// 1125.439 us; speedup vs baseline: 1.6038x; 1.6038x over previous
//
#include <hip/hip_runtime.h>

#define TT 4096
#define BB 128
#define L2E 1.4426950408889634f

typedef unsigned uv2 __attribute__((ext_vector_type(2)));
typedef float v2f __attribute__((ext_vector_type(2)));

__device__ __forceinline__ float fexp2(float a) {
  return __builtin_amdgcn_exp2f(a);  // v_exp_f32: 2^a
}

__device__ __forceinline__ float bpermf(int idx_bytes, float v) {
  return __int_as_float(__builtin_amdgcn_ds_bpermute(idx_bytes, __float_as_int(v)));
}

// Sum of p with partner half (lane ^ 32), replicated in both halves. Pure VALU.
__device__ __forceinline__ float xhalf_sum(float p) {
#if __has_builtin(__builtin_amdgcn_permlane32_swap)
  uv2 r = __builtin_amdgcn_permlane32_swap(__float_as_uint(p), __float_as_uint(p),
                                           false, false);
  return __uint_as_float(r[0]) + __uint_as_float(r[1]);
#else
  return p + bpermf((threadIdx.x ^ 32) << 2, p);
#endif
}

// gx[b,t,g]: g<64 -> 0.5*(x.w_ih[g] + b_ih[g] + b_hh[g])   (r,z; halved for cross-half sum)
//            g>=64 -> x.w_ih[g] + b_ih[g]                  (n x-side, full, per-lane)
__global__ __launch_bounds__(256) void gx_pre(
    const float* __restrict__ x, const float* __restrict__ w_ih,
    const float* __restrict__ b_ih, const float* __restrict__ b_hh,
    float* __restrict__ gx) {
  const size_t idx = (size_t)blockIdx.x * 256 + threadIdx.x;  // (b*T+t)*96+g
  const int g = (int)(idx % 96);
  const size_t bt = idx / 96;
  const float* xp = x + bt * 6;
  float acc = (g < 64) ? (b_ih[g] + b_hh[g]) : b_ih[g];
#pragma unroll
  for (int i = 0; i < 6; ++i) acc = fmaf(w_ih[g * 6 + i], xp[i], acc);
  gx[idx] = (g < 64) ? 0.5f * acc : acc;
}

// One wave per batch element. Lane l: j = l&31 owns gate rows j/32+j/64+j;
// half = l>>5 picks the 16-wide K-slice. Invariant: h register holds h[l&31].
// amdgpu_waves_per_eu(1,1): max occupancy 1 wave/EU -> VGPR budget 512, so the
// allocator keeps all weights/slots resident instead of remat'ing loads into
// the loop (the R2/R6/R7/R8 pattern: VGPR squeezed to the 64-reg 8-wave target).
// h stores go to an LDS ring (lgkm-drain ~30cy), flushed to global every 32
// steps -> no per-step vmcnt store wait on the serial chain.
__global__ __launch_bounds__(64) __attribute__((amdgpu_waves_per_eu(1, 1)))
void gru_seq(const int* __restrict__ lengths, const float* __restrict__ w_hh,
             const float* __restrict__ b_hh, const float* __restrict__ gx,
             float* __restrict__ hbuf) {
  __shared__ alignas(16) float hring[2 * 32 * 32];  // 2 buffers x 32 steps x 32 h

  const int b = blockIdx.x;
  const int l = threadIdx.x;
  const int j = l & 31;
  const int half = l >> 5;
  const int ko = half << 4;
  const int len = lengths[b];

  // raw 16-wide K-slices as float2 pairs (v_pk_fma_f32 operands)
  v2f wr2[8], wz2[8], wn2[8];
  {
    const v2f* pr = (const v2f*)(w_hh + j * 32 + ko);
    const v2f* pz = (const v2f*)(w_hh + (32 + j) * 32 + ko);
    const v2f* pn = (const v2f*)(w_hh + (64 + j) * 32 + ko);
#pragma unroll
    for (int k = 0; k < 8; ++k) wr2[k] = pr[k];
#pragma unroll
    for (int k = 0; k < 8; ++k) wz2[k] = pz[k];
#pragma unroll
    for (int k = 0; k < 8; ++k) wn2[k] = pn[k];
  }
  const float bhn = 0.5f * b_hh[64 + j];  // halved: cross-half sum doubles it

  const float* gxb = gx + (size_t)b * TT * 96;
  float* hrow = hbuf + (size_t)b * TT * 32;
  const int bko = half << 6;  // bpermute byte-index base (ko*4)

  float h = 0.0f;
  int t = 0;
  int bufsel = 0;

  // 4-deep gx prefetch slots (named; static indexing)
  float g0r, g0z, g0n, g1r, g1z, g1n, g2r, g2z, g2n, g3r, g3z, g3n;
  {
    const int t1 = (1 < len) ? 1 : len - 1, t2 = (2 < len) ? 2 : len - 1,
              t3 = (3 < len) ? 3 : len - 1;
    const float *p0 = gxb, *p1 = gxb + (size_t)t1 * 96,
                *p2 = gxb + (size_t)t2 * 96, *p3 = gxb + (size_t)t3 * 96;
    g0r = p0[j]; g0z = p0[32 + j]; g0n = p0[64 + j];
    g1r = p1[j]; g1z = p1[32 + j]; g1n = p1[64 + j];
    g2r = p2[j]; g2z = p2[32 + j]; g2n = p2[64 + j];
    g3r = p3[j]; g3z = p3[32 + j]; g3n = p3[64 + j];
  }

  // flush ring buffer bufsel: steps [base, base+cnt) -> global, float4 lanes
  auto flush = [&](int base, int cnt) {
    const float4* src = (const float4*)(hring + bufsel * 1024);
    float4* dst = (float4*)(hrow + (size_t)base * 32);
    const int n4 = cnt * 8;  // cnt*32 floats / 4
    for (int q = l; q < n4; q += 64) dst[q] = src[q];
    bufsel ^= 1;
  };

  auto step = [&](float& GR, float& GZ, float& GN) {
    // broadcast this half's 16 h values into 8 register pairs
    v2f hbv[8];
#pragma unroll
    for (int k = 0; k < 8; ++k) {
      hbv[k][0] = bpermf(bko + (k << 3), h);
      hbv[k][1] = bpermf(bko + (k << 3) + 4, h);
    }

    const float xr_ = GR, xz_ = GZ, xn_ = GN;
    // refill this slot for t+4 (completes within the next 3 iterations)
    {
      const int tp = (t + 4 < len) ? (t + 4) : (len - 1);
      const float* gp = gxb + (size_t)tp * 96;
      GR = gp[j]; GZ = gp[32 + j]; GN = gp[64 + j];
    }

    // 48 MACs as 24 v_pk_fma_f32, 8-deep chains
    v2f ar = {xr_, 0.f}, az = {xz_, 0.f}, an = {bhn, 0.f};
#pragma unroll
    for (int k = 0; k < 8; ++k) {
      ar = __builtin_elementwise_fma(wr2[k], hbv[k], ar);
      az = __builtin_elementwise_fma(wz2[k], hbv[k], az);
      an = __builtin_elementwise_fma(wn2[k], hbv[k], an);
    }
    const float sr = xhalf_sum(ar[0] + ar[1]);
    const float r = __builtin_amdgcn_rcpf(1.0f + fexp2(-L2E * sr));
    const float sz = xhalf_sum(az[0] + az[1]);
    const float z = __builtin_amdgcn_rcpf(1.0f + fexp2(-L2E * sz));
    const float hn = xhalf_sum(an[0] + an[1]);
    const float ap = fmaf(r, hn, xn_);
    const float qq = __builtin_amdgcn_rcpf(1.0f + fexp2(-2.0f * L2E * ap));
    const float nn = fmaf(2.0f, qq, -1.0f);
    h = fmaf(z, h - nn, nn);

    // LDS ring store (both halves write identical values to same address)
    hring[bufsel * 1024 + (t & 31) * 32 + j] = h;
    if ((t & 31) == 31) flush(t - 31, 32);
    ++t;
  };

  while (t + 4 <= len) {
    step(g0r, g0z, g0n);
    step(g1r, g1z, g1n);
    step(g2r, g2z, g2n);
    step(g3r, g3z, g3n);
  }
  if (t < len) step(g0r, g0z, g0n);
  if (t < len) step(g1r, g1z, g1n);
  if (t < len) step(g2r, g2z, g2n);

  const int rem = len & 31;
  if (rem) flush(len - rem, rem);
}

// out[b,t,:] = (t < len[b]) ? h[b,t,:] @ fc_w^T + fc_b : fc_b
__global__ __launch_bounds__(256) void fc_apply(
    const float* __restrict__ hbuf, const int* __restrict__ lengths,
    const float* __restrict__ fc_w, const float* __restrict__ fc_b,
    float* __restrict__ out) {
  const int idx = blockIdx.x * 256 + threadIdx.x;  // flattened (b,t)
  const int b = idx >> 12;
  const int t = idx & (TT - 1);
  const float fb0 = fc_b[0], fb1 = fc_b[1];
  float* op = out + (size_t)idx * 2;
  if (t >= lengths[b]) {
    op[0] = fb0;
    op[1] = fb1;
    return;
  }
  const float4* hp = (const float4*)(hbuf + (size_t)idx * 32);
  const float4* w0 = (const float4*)(fc_w);
  const float4* w1 = (const float4*)(fc_w + 32);
  float o0 = 0.f, o1 = 0.f;
#pragma unroll
  for (int q = 0; q < 8; ++q) {
    const float4 hv = hp[q], a = w0[q], c = w1[q];
    o0 += hv.x * a.x + hv.y * a.y + hv.z * a.z + hv.w * a.w;
    o1 += hv.x * c.x + hv.y * c.y + hv.z * c.z + hv.w * c.w;
  }
  op[0] = o0 + fb0;
  op[1] = o1 + fb1;
}

// Fallback (ws too small): self-contained single kernel.
__global__ __launch_bounds__(64) void gru_fallback(
    const float* __restrict__ x, const int* __restrict__ lengths,
    const float* __restrict__ w_ih, const float* __restrict__ w_hh,
    const float* __restrict__ b_ih, const float* __restrict__ b_hh,
    const float* __restrict__ fc_w, const float* __restrict__ fc_b,
    float* __restrict__ out) {
  const int b = blockIdx.x;
  const int l = threadIdx.x;
  const int j = l & 31;
  const int half = l >> 5;
  const int ko = half << 4;
  const int len = lengths[b];

  float wr[16], wz[16], wn[16];
#pragma unroll
  for (int k = 0; k < 16; ++k) wr[k] = w_hh[j * 32 + ko + k] * L2E;
#pragma unroll
  for (int k = 0; k < 16; ++k) wz[k] = w_hh[(32 + j) * 32 + ko + k] * L2E;
#pragma unroll
  for (int k = 0; k < 16; ++k) wn[k] = w_hh[(64 + j) * 32 + ko + k] * (2.0f * L2E);
  float wxr[6], wxz[6], wxn[6];
#pragma unroll
  for (int i = 0; i < 6; ++i) wxr[i] = w_ih[j * 6 + i] * (0.5f * L2E);
#pragma unroll
  for (int i = 0; i < 6; ++i) wxz[i] = w_ih[(32 + j) * 6 + i] * (0.5f * L2E);
#pragma unroll
  for (int i = 0; i < 6; ++i) wxn[i] = w_ih[(64 + j) * 6 + i] * (2.0f * L2E);
  const float br = (b_ih[j] + b_hh[j]) * (0.5f * L2E);
  const float bz = (b_ih[32 + j] + b_hh[32 + j]) * (0.5f * L2E);
  const float bxn = b_ih[64 + j] * (2.0f * L2E);
  const float bhn = b_hh[64 + j] * L2E;
  const float fcw = fc_w[half * 32 + j];
  const float fcb = fc_b[half];

  const float* xb = x + (size_t)b * (TT * 6);
  float* ob = out + (size_t)b * (TT * 2);
  const int bko = half << 6;
  float h = 0.0f;

  v2f cx[3], nx[3];
  {
    const v2f* xp = (const v2f*)xb;
    cx[0] = xp[0]; cx[1] = xp[1]; cx[2] = xp[2];
  }
  for (int t = 0; t < len; ++t) {
    const int tn = (t + 1 < len) ? (t + 1) : t;
    const v2f* xp = (const v2f*)(xb + tn * 6);
    nx[0] = xp[0]; nx[1] = xp[1]; nx[2] = xp[2];
    float xr = br, xz = bz, xn = bxn;
#pragma unroll
    for (int i = 0; i < 3; ++i) {
      const float c0 = cx[i][0], c1 = cx[i][1];
      xr = fmaf(wxr[2 * i], c0, xr); xr = fmaf(wxr[2 * i + 1], c1, xr);
      xz = fmaf(wxz[2 * i], c0, xz); xz = fmaf(wxz[2 * i + 1], c1, xz);
      xn = fmaf(wxn[2 * i], c0, xn); xn = fmaf(wxn[2 * i + 1], c1, xn);
    }
    float hbv[16];
#pragma unroll
    for (int k = 0; k < 16; ++k) hbv[k] = bpermf(bko + (k << 2), h);
    float ar0 = xr, ar1 = 0.f, az0 = xz, az1 = 0.f, an0 = bhn, an1 = 0.f;
#pragma unroll
    for (int k = 0; k < 8; ++k) {
      ar0 = fmaf(wr[k], hbv[k], ar0);
      ar1 = fmaf(wr[k + 8], hbv[k + 8], ar1);
      az0 = fmaf(wz[k], hbv[k], az0);
      az1 = fmaf(wz[k + 8], hbv[k + 8], az1);
      an0 = fmaf(wn[k], hbv[k], an0);
      an1 = fmaf(wn[k + 8], hbv[k + 8], an1);
    }
    const float sr = xhalf_sum(ar0 + ar1);
    const float r = __builtin_amdgcn_rcpf(1.0f + fexp2(-sr));
    const float sz = xhalf_sum(az0 + az1);
    const float z = __builtin_amdgcn_rcpf(1.0f + fexp2(-sz));
    const float hn = xhalf_sum(an0 + an1);
    const float ap = fmaf(r, hn, xn);
    const float qq = __builtin_amdgcn_rcpf(1.0f + fexp2(-ap));
    const float nn = fmaf(2.0f, qq, -1.0f);
    h = fmaf(z, h - nn, nn);
    float p = h * fcw;
    p += __shfl_xor(p, 1);
    p += __shfl_xor(p, 2);
    p += __shfl_xor(p, 4);
    p += __shfl_xor(p, 8);
    p += __shfl_xor(p, 16);
    if (j == 0) ob[t * 2 + half] = p + fcb;
#pragma unroll
    for (int i = 0; i < 3; ++i) cx[i] = nx[i];
  }
  const float fb0 = fc_b[0], fb1 = fc_b[1];
  for (int idx = len * 2 + l; idx < TT * 2; idx += 64)
    ob[idx] = (idx & 1) ? fb1 : fb0;
}

extern "C" void kernel_launch(void* const* d_in, const int* in_sizes, int n_in,
                              void* d_out, int out_size, void* d_ws, size_t ws_size,
                              hipStream_t stream) {
  const float* x       = (const float*)d_in[0];
  const int*   lengths = (const int*)d_in[1];
  const float* w_ih    = (const float*)d_in[2];
  const float* w_hh    = (const float*)d_in[3];
  const float* b_ih    = (const float*)d_in[4];
  const float* b_hh    = (const float*)d_in[5];
  const float* fc_w    = (const float*)d_in[6];
  const float* fc_b    = (const float*)d_in[7];
  float* outp = (float*)d_out;

  const size_t hbuf_elems = (size_t)BB * TT * 32;               // 64 MB
  const size_t gx_elems   = (size_t)BB * TT * 96;               // 192 MB
  const size_t need = (hbuf_elems + gx_elems) * sizeof(float);  // 256 MB
  if (ws_size >= need) {
    float* hbuf = (float*)d_ws;
    float* gx = (float*)d_ws + hbuf_elems;
    hipLaunchKernelGGL(gx_pre, dim3((BB * TT * 96) / 256), dim3(256), 0, stream,
                       x, w_ih, b_ih, b_hh, gx);
    hipLaunchKernelGGL(gru_seq, dim3(BB), dim3(64), 0, stream,
                       lengths, w_hh, b_hh, gx, hbuf);
    hipLaunchKernelGGL(fc_apply, dim3((BB * TT) / 256), dim3(256), 0, stream,
                       hbuf, lengths, fc_w, fc_b, outp);
  } else {
    hipLaunchKernelGGL(gru_fallback, dim3(BB), dim3(64), 0, stream,
                       x, lengths, w_ih, w_hh, b_ih, b_hh, fc_w, fc_b, outp);
  }
}